// Round 7
// baseline (54.189 us; speedup 1.0000x reference)
//
#include <hip/hip_runtime.h>
#include <math.h>

#define NFACE 512
#define NPIX  (256 * 256)
#define DXS   (2.0f / 256.0f)
#define NACC  64

// Camera constants (input-independent, folded from the reference):
#define EYEX 2.732f
#define EYEZ (-1.6728675276352845e-16f)
#define CC0  (6.123233995736766e-17f)

// ws layout (floats): fd[513*16] = 8208 | acc[64] @ 8256 | counter @ 8320

// Per-face record, 16 floats, coefs pre-normalized by 1/denom (sign folded):
//   [0..8]  A0,B0,C0, A1,B1,C1, A2,B2,C2 : wn_k = A_k*Py + B_k*Px + C_k
//   [9..11] DA,DB,DC : depth = DA*Py + DB*Px + DC  (depth>0 whenever inside:
//           camera-space z in [1.73,3.73] for all verts)
//   [12..15] xmin,xmax,ymin,ymax screen bbox (+margin)
// Degenerate faces & the dummy face NFACE: C0=-1 (never inside), empty bbox.
__global__ __launch_bounds__(256) void setup_faces(
    const float* __restrict__ verts,   // (642,3)
    const int*   __restrict__ faces,   // (512,3)
    float* __restrict__ ws,            // workspace (see layout)
    float* __restrict__ out)           // scalar loss (zeroed here)
{
    int f = blockIdx.x * 256 + threadIdx.x;
    if (f == 0) {
        *out = 0.0f;
        *((unsigned*)(ws + 8320)) = 0u;   // finalize counter
    }
    if (f < NACC) ws[8256 + f] = 0.0f;    // partial-sum accumulators
    if (f > NFACE) return;

    float o[16];
#pragma unroll
    for (int k = 0; k < 16; ++k) o[k] = 0.f;
    o[2]  = -1.0f;                  // never inside
    o[12] = 2e30f;  o[13] = -2e30f; // empty bbox
    o[14] = 2e30f;  o[15] = -2e30f;

    if (f < NFACE) {
        float vx[3], vy[3], vz[3];
#pragma unroll
        for (int k = 0; k < 3; ++k) {
            int vi = faces[f * 3 + k];
            float px = verts[vi * 3 + 0];
            float py = verts[vi * 3 + 1];
            float pz = verts[vi * 3 + 2];
            float dx = px - EYEX;
            float dz = pz - EYEZ;
            vx[k] = CC0 * dx + dz;
            vy[k] = py;
            vz[k] = -dx + CC0 * dz;
        }
        float ax = vx[0], ay = vy[0];
        float bx = vx[1], by = vy[1];
        float cx = vx[2], cy = vy[2];
        float denom = (bx - ax) * (cy - ay) - (by - ay) * (cx - ax);
        if (fabsf(denom) > 1e-8f) {
            float s  = (denom >= 0.f) ? 1.f : -1.f;
            float si = s / fabsf(denom);          // == 1/denom
            float e0x = cx - bx, e0y = cy - by;
            float e1x = ax - cx, e1y = ay - cy;
            float e2x = bx - ax, e2y = by - ay;
            o[0] = e0x * si;  o[1] = -e0y * si;  o[2] = (e0y * bx - e0x * by) * si;
            o[3] = e1x * si;  o[4] = -e1y * si;  o[5] = (e1y * cx - e1x * cy) * si;
            o[6] = e2x * si;  o[7] = -e2y * si;  o[8] = (e2y * ax - e2x * ay) * si;
            o[9]  = o[0] * vz[0] + o[3] * vz[1] + o[6] * vz[2];   // DA
            o[10] = o[1] * vz[0] + o[4] * vz[1] + o[7] * vz[2];   // DB
            o[11] = o[2] * vz[0] + o[5] * vz[1] + o[8] * vz[2];   // DC
            o[12] = fminf(fminf(ax, bx), cx) - 1e-4f;
            o[13] = fmaxf(fmaxf(ax, bx), cx) + 1e-4f;
            o[14] = fminf(fminf(ay, by), cy) - 1e-4f;
            o[15] = fmaxf(fmaxf(ay, by), cy) + 1e-4f;
        }
    }
    float4* fo = (float4*)(ws + f * 16);
    fo[0] = make_float4(o[0], o[1], o[2], o[3]);
    fo[1] = make_float4(o[4], o[5], o[6], o[7]);
    fo[2] = make_float4(o[8], o[9], o[10], o[11]);
    fo[3] = make_float4(o[12], o[13], o[14], o[15]);
}

// Wave = one 8-px strip (8192 strips, 2048 blocks x 4 waves). Per wave:
// ballot-compacted bbox-cull list, software-pipelined list raster
// (lane=face, 8 px inner, pack (depth_bits&~511)|face, u32-min butterfly),
// then spread-accumulator + last-block finalize (no same-address atomic tail).
__global__ __launch_bounds__(256, 6) void raster_loss(
    const float4* __restrict__ fd4,    // (513,4) float4 rows
    const float* __restrict__ tex,     // (512,4,4,4,3)
    const float* __restrict__ ref,     // (3,256,256)
    float* __restrict__ ws,            // acc @ 8256, counter @ 8320
    float* __restrict__ out)
{
    __shared__ unsigned short lists[4][512];
    __shared__ float wsum[4];
    __shared__ int lastflag;

    float* acc = ws + 8256;
    unsigned* cntr = (unsigned*)(ws + 8320);

    int lane = threadIdx.x & 63;
    int wid  = threadIdx.x >> 6;
    int strip = wid * 2048 + blockIdx.x;   // 0..8191
    int pbase = strip * 8;
    int row   = pbase >> 8;
    int ib    = pbase & 255;
    float Py = 1.0f - (row + 0.5f) * DXS;
    float x0 = (ib + 0.5f) * DXS - 1.0f;
    float x1 = x0 + 7.0f * DXS;

    // ---- bbox cull -> compacted per-wave list ----
    unsigned short* mylist = lists[wid];
    int cnt = 0;
#pragma unroll
    for (int r = 0; r < 8; ++r) {
        int f = r * 64 + lane;
        float4 bb = fd4[f * 4 + 3];   // xmin,xmax,ymin,ymax
        bool pred = (bb.x <= x1) & (bb.y >= x0) & (bb.z <= Py) & (bb.w >= Py);
        unsigned long long m = __ballot(pred);
        if (pred) {
            int ofs = cnt + (int)__popcll(m & ((1ull << lane) - 1ull));
            mylist[ofs] = (unsigned short)f;
        }
        cnt += (int)__popcll(m);
    }

    // ---- software-pipelined list raster ----
    unsigned pk[8];
#pragma unroll
    for (int q = 0; q < 8; ++q) pk[q] = 0xFFFFFFFFu;

    int nit = (cnt + 63) >> 6;
    int fi = (lane < cnt) ? (int)mylist[lane] : NFACE;
    const float4* rp = fd4 + (size_t)fi * 4;
    float4 q0 = rp[0], q1 = rp[1], q2 = rp[2];
    int curf = fi;

    for (int it = 0; it < nit; ++it) {
        // prefetch next iteration's records (dummy when past end)
        int si2 = (it + 1) * 64 + lane;
        int fi2 = (si2 < cnt) ? (int)mylist[si2] : NFACE;
        const float4* rp2 = fd4 + (size_t)fi2 * 4;
        float4 p0 = rp2[0], p1 = rp2[1], p2 = rp2[2];

        float w0b = fmaf(q0.x, Py, fmaf(q0.y, x0, q0.z));
        float w1b = fmaf(q0.w, Py, fmaf(q1.x, x0, q1.y));
        float w2b = fmaf(q1.z, Py, fmaf(q1.w, x0, q2.x));
        float dpb = fmaf(q2.y, Py, fmaf(q2.z, x0, q2.w));
        float d0 = q0.y * DXS, d1 = q1.x * DXS, d2 = q1.w * DXS, dd = q2.z * DXS;
        unsigned idb = (unsigned)curf;
#pragma unroll
        for (int q = 0; q < 8; ++q) {
            float tf = (float)q;
            float w0  = fmaf(tf, d0, w0b);
            float w1  = fmaf(tf, d1, w1b);
            float w2  = fmaf(tf, d2, w2b);
            float dep = fmaf(tf, dd, dpb);
            float mn  = fminf(fminf(w0, w1), w2);
            unsigned cand = (__float_as_uint(dep) & 0xFFFFFE00u) | idb;
            cand = (mn >= 0.f) ? cand : 0xFFFFFFFFu;
            pk[q] = pk[q] < cand ? pk[q] : cand;
        }
        q0 = p0; q1 = p1; q2 = p2; curf = fi2;
    }

    // ---- 8 interleaved u32-min butterflies across the wave ----
#pragma unroll
    for (int st = 1; st < 64; st <<= 1) {
#pragma unroll
        for (int q = 0; q < 8; ++q) {
            unsigned o = (unsigned)__shfl_xor((int)pk[q], st, 64);
            pk[q] = pk[q] < o ? pk[q] : o;
        }
    }
    unsigned mypack = 0xFFFFFFFFu;
#pragma unroll
    for (int q = 0; q < 8; ++q)
        mypack = (lane == q) ? pk[q] : mypack;

    // ---- epilogue: lanes 0..7 each finish one pixel ----
    float loss = 0.f;
    if (lane < 8) {
        int p = pbase + lane;
        float Px = fmaf((float)lane, DXS, x0);
        float col0 = 0.f, col1 = 0.f, col2 = 0.f;
        if (mypack != 0xFFFFFFFFu) {       // hit
            int best = (int)(mypack & 511u);
            const float4* bp = fd4 + (size_t)best * 4;
            float4 b0 = bp[0], b1 = bp[1], b2 = bp[2];
            float w0 = fmaf(b0.y, Px, fmaf(b0.x, Py, b0.z));
            float w1 = fmaf(b1.x, Px, fmaf(b0.w, Py, b1.y));
            float w2 = fmaf(b1.w, Px, fmaf(b1.z, Py, b2.x));
            int t0 = (int)rintf(w0 * 3.0f); t0 = t0 < 0 ? 0 : (t0 > 3 ? 3 : t0);
            int t1 = (int)rintf(w1 * 3.0f); t1 = t1 < 0 ? 0 : (t1 > 3 ? 3 : t1);
            int t2 = (int)rintf(w2 * 3.0f); t2 = t2 < 0 ? 0 : (t2 > 3 ? 3 : t2);
            const float* tp = tex + ((((best * 4 + t0) * 4 + t1) * 4 + t2) * 3);
            col0 = tanhf(tp[0]);
            col1 = tanhf(tp[1]);
            col2 = tanhf(tp[2]);
        }
        float r0 = ref[0 * NPIX + p];
        float r1 = ref[1 * NPIX + p];
        float r2 = ref[2 * NPIX + p];
        float e0 = col0 - r0, e1 = col1 - r1, e2 = col2 - r2;
        loss = e0 * e0 + e1 * e1 + e2 * e2;
    }

    // ---- block reduce -> spread accumulators -> last-block finalize ----
    for (int off = 32; off > 0; off >>= 1)
        loss += __shfl_down(loss, off, 64);
    if (lane == 0) wsum[wid] = loss;
    if (threadIdx.x == 0) lastflag = 0;
    __syncthreads();
    if (threadIdx.x == 0) {
        float bsum = wsum[0] + wsum[1] + wsum[2] + wsum[3];
        atomicAdd(&acc[blockIdx.x & (NACC - 1)], bsum);
        __threadfence();
        unsigned old = atomicAdd(cntr, 1u);
        if (old == gridDim.x - 1) lastflag = 1;
    }
    __syncthreads();
    if (lastflag && wid == 0) {
        __threadfence();
        float v = (lane < NACC) ? atomicAdd(&acc[lane], 0.0f) : 0.0f;
        for (int off = 32; off > 0; off >>= 1)
            v += __shfl_down(v, off, 64);
        if (lane == 0) out[0] = v;
    }
}

extern "C" void kernel_launch(void* const* d_in, const int* in_sizes, int n_in,
                              void* d_out, int out_size, void* d_ws, size_t ws_size,
                              hipStream_t stream) {
    const float* verts = (const float*)d_in[0];
    const float* tex   = (const float*)d_in[1];
    const float* ref   = (const float*)d_in[2];
    const int*   faces = (const int*)d_in[3];
    float* out = (float*)d_out;
    float* ws  = (float*)d_ws;   // fd table + accumulators + counter

    setup_faces<<<3, 256, 0, stream>>>(verts, faces, ws, out);
    // 8192 strips (8 px each), 4 waves/block -> 2048 blocks.
    raster_loss<<<2048, 256, 0, stream>>>((const float4*)ws, tex, ref, ws, out);
}

// Round 8
// 32.435 us; speedup vs baseline: 1.6707x; 1.6707x over previous
//
#include <hip/hip_runtime.h>
#include <math.h>

#define NFACE 512
#define NVERT 642
#define NPIX  (256 * 256)
#define DXS   (2.0f / 256.0f)

// Camera constants (input-independent, folded from the reference):
#define EYEX 2.732f
#define EYEZ (-1.6728675276352845e-16f)
#define CC0  (6.123233995736766e-17f)

// Fully fused: grid = 256 blocks (1 per CU, single scheduling pass), block =
// one 16x16 pixel tile. Per block:
//   0) verts -> LDS (coalesced)
//   1) each thread sets up 2 faces into the LDS record table and immediately
//      bbox-culls them against the tile (unordered LDS list via atomic —
//      safe: pack-min is order-invariant, ties -> smaller face index, same
//      as jnp.argmin first-index)
//   2) per-pixel loop over culled list: broadcast ds_read_b128 + pure VALU
//   3) local epilogue (bary -> texel -> tanh -> sq-err), block reduce,
//      one atomicAdd per block.
// Face record (float4 x4): q0=(A0,B0,C0,A1) q1=(B1,C1,A2,B2) q2=(C2,DA,DB,DC)
// bb=(xmin,xmax,ymin,ymax). wn_k = A_k*Py + B_k*Px + C_k equals the
// reference's w_k/denom (sign folded); depth = DA*Py + DB*Px + DC.
// depth>0 is implied by inside: wn sum to 1, camera z in [1.73,3.73]>0.
__global__ __launch_bounds__(256) void render_loss(
    const float* __restrict__ verts,   // (642,3)
    const int*   __restrict__ faces,   // (512,3)
    const float* __restrict__ tex,     // (512,4,4,4,3)
    const float* __restrict__ ref,     // (3,256,256)
    float* __restrict__ out)           // scalar (pre-zeroed)
{
    __shared__ float  sverts[NVERT * 3];
    __shared__ float4 sf4[NFACE * 4];
    __shared__ unsigned short list[NFACE];
    __shared__ int   scnt;
    __shared__ float wsum[4];

    int tid = threadIdx.x;
    if (tid == 0) scnt = 0;

    // ---- phase 0: stage vertices into LDS (coalesced) ----
    for (int k = tid; k < NVERT * 3; k += 256) sverts[k] = verts[k];
    __syncthreads();

    // tile extents
    int tileX = (blockIdx.x & 15) << 4;
    int tileY = (blockIdx.x >> 4) << 4;
    float xlo = (tileX + 0.5f)  * DXS - 1.0f;
    float xhi = (tileX + 15.5f) * DXS - 1.0f;
    float yhi = 1.0f - (tileY + 0.5f)  * DXS;   // top (larger y)
    float ylo = 1.0f - (tileY + 15.5f) * DXS;   // bottom

    // ---- phase 1: face setup + self-cull (2 faces per thread) ----
    for (int f = tid; f < NFACE; f += 256) {
        int i0 = faces[f * 3 + 0];
        int i1 = faces[f * 3 + 1];
        int i2 = faces[f * 3 + 2];
        float vx[3], vy[3], vz[3];
        int vi[3] = {i0, i1, i2};
#pragma unroll
        for (int k = 0; k < 3; ++k) {
            float px = sverts[vi[k] * 3 + 0];
            float py = sverts[vi[k] * 3 + 1];
            float pz = sverts[vi[k] * 3 + 2];
            float dx = px - EYEX;
            float dz = pz - EYEZ;
            vx[k] = CC0 * dx + dz;
            vy[k] = py;
            vz[k] = -dx + CC0 * dz;
        }
        float ax = vx[0], ay = vy[0];
        float bx = vx[1], by = vy[1];
        float cx = vx[2], cy = vy[2];
        float denom = (bx - ax) * (cy - ay) - (by - ay) * (cx - ax);
        bool nondeg = fabsf(denom) > 1e-8f;

        float o[12];
#pragma unroll
        for (int k = 0; k < 12; ++k) o[k] = 0.f;
        float bxmn = 2e30f, bxmx = -2e30f, bymn = 2e30f, bymx = -2e30f;
        if (nondeg) {
            float s  = (denom >= 0.f) ? 1.f : -1.f;
            float si = s / fabsf(denom);          // == 1/denom
            float e0x = cx - bx, e0y = cy - by;
            float e1x = ax - cx, e1y = ay - cy;
            float e2x = bx - ax, e2y = by - ay;
            o[0] = e0x * si;  o[1] = -e0y * si;  o[2] = (e0y * bx - e0x * by) * si;
            o[3] = e1x * si;  o[4] = -e1y * si;  o[5] = (e1y * cx - e1x * cy) * si;
            o[6] = e2x * si;  o[7] = -e2y * si;  o[8] = (e2y * ax - e2x * ay) * si;
            o[9]  = o[0] * vz[0] + o[3] * vz[1] + o[6] * vz[2];   // DA
            o[10] = o[1] * vz[0] + o[4] * vz[1] + o[7] * vz[2];   // DB
            o[11] = o[2] * vz[0] + o[5] * vz[1] + o[8] * vz[2];   // DC
            bxmn = fminf(fminf(ax, bx), cx) - 1e-4f;
            bxmx = fmaxf(fmaxf(ax, bx), cx) + 1e-4f;
            bymn = fminf(fminf(ay, by), cy) - 1e-4f;
            bymx = fmaxf(fmaxf(ay, by), cy) + 1e-4f;
        }
        sf4[f * 4 + 0] = make_float4(o[0], o[1], o[2],  o[3]);
        sf4[f * 4 + 1] = make_float4(o[4], o[5], o[6],  o[7]);
        sf4[f * 4 + 2] = make_float4(o[8], o[9], o[10], o[11]);
        sf4[f * 4 + 3] = make_float4(bxmn, bxmx, bymn, bymx);

        // self-cull against this block's tile
        if (nondeg & (bxmn <= xhi) & (bxmx >= xlo) & (bymn <= yhi) & (bymx >= ylo)) {
            int ofs = atomicAdd(&scnt, 1);
            list[ofs] = (unsigned short)f;
        }
    }
    __syncthreads();
    int cnt = scnt;

    // ---- phase 2: per-pixel raster over culled list (LDS broadcast) ----
    int i = tileX + (tid & 15);
    int j = tileY + (tid >> 4);
    float Px = (i + 0.5f) * DXS - 1.0f;
    float Py = 1.0f - (j + 0.5f) * DXS;

    unsigned best = 0xFFFFFFFFu;
    for (int k = 0; k < cnt; ++k) {
        int fi = (int)list[k];                 // broadcast
        float4 q0 = sf4[fi * 4 + 0];           // broadcast ds_read_b128
        float4 q1 = sf4[fi * 4 + 1];
        float4 q2 = sf4[fi * 4 + 2];
        float w0  = fmaf(q0.x, Py, fmaf(q0.y, Px, q0.z));
        float w1  = fmaf(q0.w, Py, fmaf(q1.x, Px, q1.y));
        float w2  = fmaf(q1.z, Py, fmaf(q1.w, Px, q2.x));
        float dep = fmaf(q2.y, Py, fmaf(q2.z, Px, q2.w));
        float mn  = fminf(fminf(w0, w1), w2);
        unsigned cand = (__float_as_uint(dep) & 0xFFFFFE00u) | (unsigned)fi;
        cand = (mn >= 0.f) ? cand : 0xFFFFFFFFu;
        best = best < cand ? best : cand;
    }

    // ---- phase 3: epilogue (local, no redistribution) ----
    int p = j * 256 + i;
    float col0 = 0.f, col1 = 0.f, col2 = 0.f;
    if (best != 0xFFFFFFFFu) {
        int bf = (int)(best & 511u);
        float4 q0 = sf4[bf * 4 + 0];
        float4 q1 = sf4[bf * 4 + 1];
        float4 q2 = sf4[bf * 4 + 2];
        float w0 = fmaf(q0.x, Py, fmaf(q0.y, Px, q0.z));
        float w1 = fmaf(q0.w, Py, fmaf(q1.x, Px, q1.y));
        float w2 = fmaf(q1.z, Py, fmaf(q1.w, Px, q2.x));
        int t0 = (int)rintf(w0 * 3.0f); t0 = t0 < 0 ? 0 : (t0 > 3 ? 3 : t0);
        int t1 = (int)rintf(w1 * 3.0f); t1 = t1 < 0 ? 0 : (t1 > 3 ? 3 : t1);
        int t2 = (int)rintf(w2 * 3.0f); t2 = t2 < 0 ? 0 : (t2 > 3 ? 3 : t2);
        const float* tp = tex + ((((bf * 4 + t0) * 4 + t1) * 4 + t2) * 3);
        col0 = tanhf(tp[0]);
        col1 = tanhf(tp[1]);
        col2 = tanhf(tp[2]);
    }
    float r0 = ref[0 * NPIX + p];
    float r1 = ref[1 * NPIX + p];
    float r2 = ref[2 * NPIX + p];
    float e0 = col0 - r0, e1 = col1 - r1, e2 = col2 - r2;
    float loss = e0 * e0 + e1 * e1 + e2 * e2;

    // ---- block reduce, one atomic per block ----
    for (int off = 32; off > 0; off >>= 1)
        loss += __shfl_down(loss, off, 64);
    int lane = tid & 63;
    int wid  = tid >> 6;
    if (lane == 0) wsum[wid] = loss;
    __syncthreads();
    if (tid == 0)
        atomicAdd(out, wsum[0] + wsum[1] + wsum[2] + wsum[3]);
}

extern "C" void kernel_launch(void* const* d_in, const int* in_sizes, int n_in,
                              void* d_out, int out_size, void* d_ws, size_t ws_size,
                              hipStream_t stream) {
    const float* verts = (const float*)d_in[0];
    const float* tex   = (const float*)d_in[1];
    const float* ref   = (const float*)d_in[2];
    const int*   faces = (const int*)d_in[3];
    float* out = (float*)d_out;

    hipMemsetAsync(out, 0, sizeof(float), stream);
    // 256 tiles of 16x16 px, one block per CU, single pass.
    render_loss<<<256, 256, 0, stream>>>(verts, faces, tex, ref, out);
}

// Round 9
// 21.441 us; speedup vs baseline: 2.5274x; 1.5127x over previous
//
#include <hip/hip_runtime.h>
#include <math.h>

#define NFACE 512
#define NVERT 642
#define NPIX  (256 * 256)
#define DXS   (2.0f / 256.0f)

// Camera constants (input-independent, folded from the reference):
#define EYEX 2.732f
#define EYEZ (-1.6728675276352845e-16f)
#define CC0  (6.123233995736766e-17f)

// Fused renderer, grid = 256 blocks (1/CU), block = 16x16 pixel tile.
// Phase 1 classifies every face against the tile using exact per-edge
// corner bounds (affine => extremes at corners):
//   reject      if any edge wmax < -m   (no pixel can be inside)
//   full-inside if all edges wmin > +m  (every pixel inside: test = depth only)
//   else partial (exact 3-edge per-pixel test)
// m scales with coefficient magnitude so slivers stay exact (partial path).
// Records: w_k = A_k*Py + B_k*Px + C_k (== reference w_k/denom, sign folded),
// w2 = 1 - w0 - w1;  depth = DA*Py + DB*Px + DC.  Inside => depth > 0
// (barycentrics >= 0 sum to 1, camera z in [1.73,3.73]).
// Argmin via pack (depth_bits & ~511) | face, u32 min: order-invariant,
// ties -> smaller face index (matches jnp.argmin first-index).
__global__ __launch_bounds__(256) void render_loss(
    const float* __restrict__ verts,   // (642,3)
    const int*   __restrict__ faces,   // (512,3)
    const float* __restrict__ tex,     // (512,4,4,4,3)
    const float* __restrict__ ref,     // (3,256,256)
    float* __restrict__ out)           // scalar (pre-zeroed)
{
    __shared__ float  sverts[NVERT * 3];
    __shared__ float4 sf0[NFACE];        // A0,B0,C0,A1   (epilogue)
    __shared__ float4 sf1[NFACE];        // B1,C1,DA,DB   (epilogue)
    __shared__ float4 flist[NFACE];      // full-inside: DA,DB,DC,fi_bits
    __shared__ float4 plist[NFACE][3];   // partial: q0,q1,(DC,fi_bits,-,-)
    __shared__ int   fcnt, pcnt;
    __shared__ float wsum[4];

    int tid = threadIdx.x;
    if (tid == 0) { fcnt = 0; pcnt = 0; }

    // ---- phase 0: stage vertices (coalesced) ----
    for (int k = tid; k < NVERT * 3; k += 256) sverts[k] = verts[k];
    __syncthreads();

    int tileX = (blockIdx.x & 15) << 4;
    int tileY = (blockIdx.x >> 4) << 4;
    float xlo = (tileX + 0.5f)  * DXS - 1.0f;
    float xhi = (tileX + 15.5f) * DXS - 1.0f;
    float yhi = 1.0f - (tileY + 0.5f)  * DXS;
    float ylo = 1.0f - (tileY + 15.5f) * DXS;

    // ---- phase 1: face setup + classify (2 faces/thread) ----
    for (int f = tid; f < NFACE; f += 256) {
        float vx[3], vy[3], vz[3];
#pragma unroll
        for (int k = 0; k < 3; ++k) {
            int vi = faces[f * 3 + k];
            float px = sverts[vi * 3 + 0];
            float py = sverts[vi * 3 + 1];
            float pz = sverts[vi * 3 + 2];
            float dx = px - EYEX;
            float dz = pz - EYEZ;
            vx[k] = CC0 * dx + dz;
            vy[k] = py;
            vz[k] = -dx + CC0 * dz;
        }
        float ax = vx[0], ay = vy[0];
        float bx = vx[1], by = vy[1];
        float cx = vx[2], cy = vy[2];
        float denom = (bx - ax) * (cy - ay) - (by - ay) * (cx - ax);
        if (fabsf(denom) <= 1e-8f) continue;      // degenerate: never visible

        float si = 1.0f / denom;                  // sign folded
        float e0x = cx - bx, e0y = cy - by;
        float e1x = ax - cx, e1y = ay - cy;
        float e2x = bx - ax, e2y = by - ay;
        float A0 = e0x * si, B0 = -e0y * si, C0 = (e0y * bx - e0x * by) * si;
        float A1 = e1x * si, B1 = -e1y * si, C1 = (e1y * cx - e1x * cy) * si;
        float A2 = e2x * si, B2 = -e2y * si, C2 = (e2y * ax - e2x * ay) * si;
        float DA = A0 * vz[0] + A1 * vz[1] + A2 * vz[2];
        float DB = B0 * vz[0] + B1 * vz[1] + B2 * vz[2];
        float DC = C0 * vz[0] + C1 * vz[1] + C2 * vz[2];

        sf0[f] = make_float4(A0, B0, C0, A1);
        sf1[f] = make_float4(B1, C1, DA, DB);

        // bbox pre-reject (cheap, conservative)
        float bxmn = fminf(fminf(ax, bx), cx), bxmx = fmaxf(fmaxf(ax, bx), cx);
        float bymn = fminf(fminf(ay, by), cy), bymx = fmaxf(fmaxf(ay, by), cy);
        if ((bxmn > xhi + 1e-5f) | (bxmx < xlo - 1e-5f) |
            (bymn > yhi + 1e-5f) | (bymx < ylo - 1e-5f)) continue;

        // exact corner bounds per edge, magnitude-scaled margin
        float wmx[3], wmn[3], mg[3];
        float As[3] = {A0, A1, A2}, Bs[3] = {B0, B1, B2}, Cs[3] = {C0, C1, C2};
#pragma unroll
        for (int k = 0; k < 3; ++k) {
            float t1 = As[k] * ylo, t2 = As[k] * yhi;
            float u1 = Bs[k] * xlo, u2 = Bs[k] * xhi;
            wmx[k] = fmaxf(t1, t2) + fmaxf(u1, u2) + Cs[k];
            wmn[k] = fminf(t1, t2) + fminf(u1, u2) + Cs[k];
            mg[k]  = (fabsf(As[k]) + fabsf(Bs[k]) + fabsf(Cs[k])) * 2e-6f;
        }
        bool rej  = (wmx[0] < -mg[0]) | (wmx[1] < -mg[1]) | (wmx[2] < -mg[2]);
        if (rej) continue;
        bool full = (wmn[0] > mg[0]) & (wmn[1] > mg[1]) & (wmn[2] > mg[2]);
        if (full) {
            int s = atomicAdd(&fcnt, 1);
            flist[s] = make_float4(DA, DB, DC, __uint_as_float((unsigned)f));
        } else {
            int s = atomicAdd(&pcnt, 1);
            plist[s][0] = make_float4(A0, B0, C0, A1);
            plist[s][1] = make_float4(B1, C1, DA, DB);
            plist[s][2] = make_float4(DC, __uint_as_float((unsigned)f), 0.f, 0.f);
        }
    }
    __syncthreads();
    int fc = fcnt, pc = pcnt;

    // ---- phase 2: per-pixel argmin over both lists (LDS broadcasts) ----
    int i = tileX + (tid & 15);
    int j = tileY + (tid >> 4);
    float Px = (i + 0.5f) * DXS - 1.0f;
    float Py = 1.0f - (j + 0.5f) * DXS;

    unsigned best = 0xFFFFFFFFu;
    for (int k = 0; k < fc; ++k) {                 // full-inside: depth only
        float4 r = flist[k];
        float dep = fmaf(r.x, Py, fmaf(r.y, Px, r.z));
        unsigned cand = (__float_as_uint(dep) & 0xFFFFFE00u) | __float_as_uint(r.w);
        best = best < cand ? best : cand;
    }
    for (int k = 0; k < pc; ++k) {                 // partial: exact 3-edge test
        float4 q0 = plist[k][0];
        float4 q1 = plist[k][1];
        float4 q2 = plist[k][2];
        float w0  = fmaf(q0.x, Py, fmaf(q0.y, Px, q0.z));
        float w1  = fmaf(q0.w, Py, fmaf(q1.x, Px, q1.y));
        float w2  = 1.0f - w0 - w1;
        float dep = fmaf(q1.z, Py, fmaf(q1.w, Px, q2.x));
        float mn  = fminf(fminf(w0, w1), w2);
        unsigned cand = (__float_as_uint(dep) & 0xFFFFFE00u) | __float_as_uint(q2.y);
        cand = (mn >= 0.f) ? cand : 0xFFFFFFFFu;
        best = best < cand ? best : cand;
    }

    // ---- phase 3: epilogue ----
    int p = j * 256 + i;
    float col0 = 0.f, col1 = 0.f, col2 = 0.f;
    if (best != 0xFFFFFFFFu) {
        int bf = (int)(best & 511u);
        float4 q0 = sf0[bf];
        float4 q1 = sf1[bf];
        float w0 = fmaf(q0.x, Py, fmaf(q0.y, Px, q0.z));
        float w1 = fmaf(q0.w, Py, fmaf(q1.x, Px, q1.y));
        float w2 = 1.0f - w0 - w1;
        int t0 = (int)rintf(w0 * 3.0f); t0 = t0 < 0 ? 0 : (t0 > 3 ? 3 : t0);
        int t1 = (int)rintf(w1 * 3.0f); t1 = t1 < 0 ? 0 : (t1 > 3 ? 3 : t1);
        int t2 = (int)rintf(w2 * 3.0f); t2 = t2 < 0 ? 0 : (t2 > 3 ? 3 : t2);
        const float* tp = tex + ((((bf * 4 + t0) * 4 + t1) * 4 + t2) * 3);
        col0 = tanhf(tp[0]);
        col1 = tanhf(tp[1]);
        col2 = tanhf(tp[2]);
    }
    float r0 = ref[0 * NPIX + p];
    float r1 = ref[1 * NPIX + p];
    float r2 = ref[2 * NPIX + p];
    float e0 = col0 - r0, e1 = col1 - r1, e2 = col2 - r2;
    float loss = e0 * e0 + e1 * e1 + e2 * e2;

    // ---- block reduce, one atomic per block ----
    for (int off = 32; off > 0; off >>= 1)
        loss += __shfl_down(loss, off, 64);
    int lane = tid & 63;
    int wid  = tid >> 6;
    if (lane == 0) wsum[wid] = loss;
    __syncthreads();
    if (tid == 0)
        atomicAdd(out, wsum[0] + wsum[1] + wsum[2] + wsum[3]);
}

extern "C" void kernel_launch(void* const* d_in, const int* in_sizes, int n_in,
                              void* d_out, int out_size, void* d_ws, size_t ws_size,
                              hipStream_t stream) {
    const float* verts = (const float*)d_in[0];
    const float* tex   = (const float*)d_in[1];
    const float* ref   = (const float*)d_in[2];
    const int*   faces = (const int*)d_in[3];
    float* out = (float*)d_out;

    hipMemsetAsync(out, 0, sizeof(float), stream);
    render_loss<<<256, 256, 0, stream>>>(verts, faces, tex, ref, out);
}

// Round 10
// 17.675 us; speedup vs baseline: 3.0659x; 1.2131x over previous
//
#include <hip/hip_runtime.h>
#include <math.h>

#define NFACE 512
#define NVERT 642
#define NPIX  (256 * 256)
#define DXS   (2.0f / 256.0f)

// Camera constants (input-independent, folded from the reference):
#define EYEX 2.732f
#define EYEZ (-1.6728675276352845e-16f)
#define CC0  (6.123233995736766e-17f)

// Fused renderer, grid = 256 blocks (1/CU), block = 16x16 pixel tile.
// Phase 1 classifies each face vs the tile by exact per-edge corner bounds
// (affine => extremes at corners): reject / full-inside / partial.
// NEW: tile-level depth pruning. depth is affine; corner bounds give
// [dmin,dmax] per face. M = min over FULL faces of (dmax + m). A full face
// is visible at every tile pixel, so zbuf(p) <= M for all p; any face with
// dmin - m > M can never win the argmin in this tile -> drop from lists.
// (Pruning only removes faces that lose in the UNquantized reference, so it
// cannot add error vs the reference.)
// Records: w_k = A_k*Py + B_k*Px + C_k (== reference w_k/denom, sign folded),
// w2 = 1 - w0 - w1; depth = DA*Py + DB*Px + DC; inside => depth > 0.
// Argmin pack: (depth_bits & ~511) | face, u32 min — order-invariant,
// ties -> smaller face index (matches jnp.argmin first-index).
__global__ __launch_bounds__(256) void render_loss(
    const float* __restrict__ verts,   // (642,3)
    const int*   __restrict__ faces,   // (512,3)
    const float* __restrict__ tex,     // (512,4,4,4,3)
    const float* __restrict__ ref,     // (3,256,256)
    float* __restrict__ out)           // scalar (pre-zeroed)
{
    __shared__ float  sverts[NVERT * 3];
    __shared__ float4 sf0[NFACE];        // A0,B0,C0,A1   (epilogue)
    __shared__ float4 sf1[NFACE];        // B1,C1,DA,DB   (epilogue)
    __shared__ float4 flist[NFACE];      // full: DA,DB,DC,fi_bits
    __shared__ float4 plist[NFACE][3];   // partial: q0,q1,(DC,fi_bits,-,-)
    __shared__ int   fcnt, pcnt;
    __shared__ unsigned Mu;
    __shared__ float wsum[4];

    int tid = threadIdx.x;
    if (tid == 0) { fcnt = 0; pcnt = 0; Mu = 0x7f800000u; }  // M = +inf

    // ---- phase 0: stage vertices (coalesced) ----
    for (int k = tid; k < NVERT * 3; k += 256) sverts[k] = verts[k];
    __syncthreads();

    int tileX = (blockIdx.x & 15) << 4;
    int tileY = (blockIdx.x >> 4) << 4;
    float xlo = (tileX + 0.5f)  * DXS - 1.0f;
    float xhi = (tileX + 15.5f) * DXS - 1.0f;
    float yhi = 1.0f - (tileY + 0.5f)  * DXS;
    float ylo = 1.0f - (tileY + 15.5f) * DXS;

    // ---- phase 1a: setup + classify (2 faces/thread, results in regs) ----
    float rc[2][9];      // A0,B0,C0,A1,B1,C1,DA,DB,DC
    int   rcls[2];       // 0=rejected, 1=full, 2=partial
    float rdmn[2];       // dmin - margin
#pragma unroll
    for (int it = 0; it < 2; ++it) {
        int f = tid + it * 256;
        rcls[it] = 0;
        float vx[3], vy[3], vz[3];
#pragma unroll
        for (int k = 0; k < 3; ++k) {
            int vi = faces[f * 3 + k];
            float px = sverts[vi * 3 + 0];
            float py = sverts[vi * 3 + 1];
            float pz = sverts[vi * 3 + 2];
            float dx = px - EYEX;
            float dz = pz - EYEZ;
            vx[k] = CC0 * dx + dz;
            vy[k] = py;
            vz[k] = -dx + CC0 * dz;
        }
        float ax = vx[0], ay = vy[0];
        float bx = vx[1], by = vy[1];
        float cx = vx[2], cy = vy[2];
        float denom = (bx - ax) * (cy - ay) - (by - ay) * (cx - ax);
        if (fabsf(denom) <= 1e-8f) continue;      // degenerate

        float si = 1.0f / denom;                  // sign folded
        float e0x = cx - bx, e0y = cy - by;
        float e1x = ax - cx, e1y = ay - cy;
        float e2x = bx - ax, e2y = by - ay;
        float A0 = e0x * si, B0 = -e0y * si, C0 = (e0y * bx - e0x * by) * si;
        float A1 = e1x * si, B1 = -e1y * si, C1 = (e1y * cx - e1x * cy) * si;
        float A2 = e2x * si, B2 = -e2y * si, C2 = (e2y * ax - e2x * ay) * si;
        float DA = A0 * vz[0] + A1 * vz[1] + A2 * vz[2];
        float DB = B0 * vz[0] + B1 * vz[1] + B2 * vz[2];
        float DC = C0 * vz[0] + C1 * vz[1] + C2 * vz[2];

        sf0[f] = make_float4(A0, B0, C0, A1);
        sf1[f] = make_float4(B1, C1, DA, DB);

        // bbox pre-reject
        float bxmn = fminf(fminf(ax, bx), cx), bxmx = fmaxf(fmaxf(ax, bx), cx);
        float bymn = fminf(fminf(ay, by), cy), bymx = fmaxf(fmaxf(ay, by), cy);
        if ((bxmn > xhi + 1e-5f) | (bxmx < xlo - 1e-5f) |
            (bymn > yhi + 1e-5f) | (bymx < ylo - 1e-5f)) continue;

        // exact corner bounds per edge, magnitude-scaled margins
        float wmx[3], wmn[3], mg[3];
        float As[3] = {A0, A1, A2}, Bs[3] = {B0, B1, B2}, Cs[3] = {C0, C1, C2};
#pragma unroll
        for (int k = 0; k < 3; ++k) {
            float t1 = As[k] * ylo, t2 = As[k] * yhi;
            float u1 = Bs[k] * xlo, u2 = Bs[k] * xhi;
            wmx[k] = fmaxf(t1, t2) + fmaxf(u1, u2) + Cs[k];
            wmn[k] = fminf(t1, t2) + fminf(u1, u2) + Cs[k];
            mg[k]  = (fabsf(As[k]) + fabsf(Bs[k]) + fabsf(Cs[k])) * 2e-6f;
        }
        if ((wmx[0] < -mg[0]) | (wmx[1] < -mg[1]) | (wmx[2] < -mg[2])) continue;
        bool full = (wmn[0] > mg[0]) & (wmn[1] > mg[1]) & (wmn[2] > mg[2]);

        // depth corner range + margin
        float t1 = DA * ylo, t2 = DA * yhi;
        float u1 = DB * xlo, u2 = DB * xhi;
        float dmx = fmaxf(t1, t2) + fmaxf(u1, u2) + DC;
        float dmn = fminf(t1, t2) + fminf(u1, u2) + DC;
        float md  = (fabsf(DA) + fabsf(DB) + fabsf(DC)) * 2e-6f + 1e-4f;
        rdmn[it] = dmn - md;
        rcls[it] = full ? 1 : 2;
        rc[it][0] = A0; rc[it][1] = B0; rc[it][2] = C0;
        rc[it][3] = A1; rc[it][4] = B1; rc[it][5] = C1;
        rc[it][6] = DA; rc[it][7] = DB; rc[it][8] = DC;
        if (full) atomicMin(&Mu, __float_as_uint(dmx + md));
    }
    __syncthreads();

    // ---- phase 1b: depth-pruned append ----
    float M = __uint_as_float(Mu);
#pragma unroll
    for (int it = 0; it < 2; ++it) {
        if (rcls[it] == 0 || rdmn[it] > M) continue;
        int f = tid + it * 256;
        float fb = __uint_as_float((unsigned)f);
        if (rcls[it] == 1) {
            int s = atomicAdd(&fcnt, 1);
            flist[s] = make_float4(rc[it][6], rc[it][7], rc[it][8], fb);
        } else {
            int s = atomicAdd(&pcnt, 1);
            plist[s][0] = make_float4(rc[it][0], rc[it][1], rc[it][2], rc[it][3]);
            plist[s][1] = make_float4(rc[it][4], rc[it][5], rc[it][6], rc[it][7]);
            plist[s][2] = make_float4(rc[it][8], fb, 0.f, 0.f);
        }
    }
    __syncthreads();
    int fc = fcnt, pc = pcnt;

    // ---- phase 2: per-pixel argmin, batched loads for ILP ----
    int i = tileX + (tid & 15);
    int j = tileY + (tid >> 4);
    float Px = (i + 0.5f) * DXS - 1.0f;
    float Py = 1.0f - (j + 0.5f) * DXS;

    unsigned best = 0xFFFFFFFFu;
    int k = 0;
    for (; k + 4 <= fc; k += 4) {
        float4 ra = flist[k + 0], rb = flist[k + 1];
        float4 rcc = flist[k + 2], rd = flist[k + 3];
        float da = fmaf(ra.x, Py, fmaf(ra.y, Px, ra.z));
        float db = fmaf(rb.x, Py, fmaf(rb.y, Px, rb.z));
        float dc = fmaf(rcc.x, Py, fmaf(rcc.y, Px, rcc.z));
        float dd = fmaf(rd.x, Py, fmaf(rd.y, Px, rd.z));
        unsigned ca = (__float_as_uint(da) & 0xFFFFFE00u) | __float_as_uint(ra.w);
        unsigned cb = (__float_as_uint(db) & 0xFFFFFE00u) | __float_as_uint(rb.w);
        unsigned cc = (__float_as_uint(dc) & 0xFFFFFE00u) | __float_as_uint(rcc.w);
        unsigned cd = (__float_as_uint(dd) & 0xFFFFFE00u) | __float_as_uint(rd.w);
        ca = ca < cb ? ca : cb;
        cc = cc < cd ? cc : cd;
        ca = ca < cc ? ca : cc;
        best = best < ca ? best : ca;
    }
    for (; k < fc; ++k) {
        float4 r = flist[k];
        float dep = fmaf(r.x, Py, fmaf(r.y, Px, r.z));
        unsigned cand = (__float_as_uint(dep) & 0xFFFFFE00u) | __float_as_uint(r.w);
        best = best < cand ? best : cand;
    }
    k = 0;
    for (; k + 2 <= pc; k += 2) {
        float4 a0 = plist[k][0], a1 = plist[k][1], a2 = plist[k][2];
        float4 b0 = plist[k+1][0], b1 = plist[k+1][1], b2 = plist[k+1][2];
        float aw0 = fmaf(a0.x, Py, fmaf(a0.y, Px, a0.z));
        float aw1 = fmaf(a0.w, Py, fmaf(a1.x, Px, a1.y));
        float aw2 = 1.0f - aw0 - aw1;
        float adp = fmaf(a1.z, Py, fmaf(a1.w, Px, a2.x));
        float amn = fminf(fminf(aw0, aw1), aw2);
        unsigned ac = (__float_as_uint(adp) & 0xFFFFFE00u) | __float_as_uint(a2.y);
        ac = (amn >= 0.f) ? ac : 0xFFFFFFFFu;
        float bw0 = fmaf(b0.x, Py, fmaf(b0.y, Px, b0.z));
        float bw1 = fmaf(b0.w, Py, fmaf(b1.x, Px, b1.y));
        float bw2 = 1.0f - bw0 - bw1;
        float bdp = fmaf(b1.z, Py, fmaf(b1.w, Px, b2.x));
        float bmn = fminf(fminf(bw0, bw1), bw2);
        unsigned bc = (__float_as_uint(bdp) & 0xFFFFFE00u) | __float_as_uint(b2.y);
        bc = (bmn >= 0.f) ? bc : 0xFFFFFFFFu;
        ac = ac < bc ? ac : bc;
        best = best < ac ? best : ac;
    }
    for (; k < pc; ++k) {
        float4 q0 = plist[k][0], q1 = plist[k][1], q2 = plist[k][2];
        float w0  = fmaf(q0.x, Py, fmaf(q0.y, Px, q0.z));
        float w1  = fmaf(q0.w, Py, fmaf(q1.x, Px, q1.y));
        float w2  = 1.0f - w0 - w1;
        float dep = fmaf(q1.z, Py, fmaf(q1.w, Px, q2.x));
        float mn  = fminf(fminf(w0, w1), w2);
        unsigned cand = (__float_as_uint(dep) & 0xFFFFFE00u) | __float_as_uint(q2.y);
        cand = (mn >= 0.f) ? cand : 0xFFFFFFFFu;
        best = best < cand ? best : cand;
    }

    // ---- phase 3: epilogue ----
    int p = j * 256 + i;
    float col0 = 0.f, col1 = 0.f, col2 = 0.f;
    if (best != 0xFFFFFFFFu) {
        int bf = (int)(best & 511u);
        float4 q0 = sf0[bf];
        float4 q1 = sf1[bf];
        float w0 = fmaf(q0.x, Py, fmaf(q0.y, Px, q0.z));
        float w1 = fmaf(q0.w, Py, fmaf(q1.x, Px, q1.y));
        float w2 = 1.0f - w0 - w1;
        int t0 = (int)rintf(w0 * 3.0f); t0 = t0 < 0 ? 0 : (t0 > 3 ? 3 : t0);
        int t1 = (int)rintf(w1 * 3.0f); t1 = t1 < 0 ? 0 : (t1 > 3 ? 3 : t1);
        int t2 = (int)rintf(w2 * 3.0f); t2 = t2 < 0 ? 0 : (t2 > 3 ? 3 : t2);
        const float* tp = tex + ((((bf * 4 + t0) * 4 + t1) * 4 + t2) * 3);
        col0 = tanhf(tp[0]);
        col1 = tanhf(tp[1]);
        col2 = tanhf(tp[2]);
    }
    float r0 = ref[0 * NPIX + p];
    float r1 = ref[1 * NPIX + p];
    float r2 = ref[2 * NPIX + p];
    float e0 = col0 - r0, e1 = col1 - r1, e2 = col2 - r2;
    float loss = e0 * e0 + e1 * e1 + e2 * e2;

    // ---- block reduce, one atomic per block ----
    for (int off = 32; off > 0; off >>= 1)
        loss += __shfl_down(loss, off, 64);
    int lane = tid & 63;
    int wid  = tid >> 6;
    if (lane == 0) wsum[wid] = loss;
    __syncthreads();
    if (tid == 0)
        atomicAdd(out, wsum[0] + wsum[1] + wsum[2] + wsum[3]);
}

extern "C" void kernel_launch(void* const* d_in, const int* in_sizes, int n_in,
                              void* d_out, int out_size, void* d_ws, size_t ws_size,
                              hipStream_t stream) {
    const float* verts = (const float*)d_in[0];
    const float* tex   = (const float*)d_in[1];
    const float* ref   = (const float*)d_in[2];
    const int*   faces = (const int*)d_in[3];
    float* out = (float*)d_out;

    hipMemsetAsync(out, 0, sizeof(float), stream);
    render_loss<<<256, 256, 0, stream>>>(verts, faces, tex, ref, out);
}